// Round 1
// baseline (228.275 us; speedup 1.0000x reference)
//
#include <hip/hip_runtime.h>
#include <stdint.h>

// Problem constants
#define B_    2
#define NQ_   1024
#define NKV_  4096
#define DQ_   1024
#define H_    16
#define DH_   64
#define INNER_ 1024

typedef unsigned short u16;
typedef uint32_t u32;
typedef __bf16 bf16x8 __attribute__((ext_vector_type(8)));
typedef float  f32x4  __attribute__((ext_vector_type(4)));

__device__ __forceinline__ u16 f2bf(float x) {           // RNE
  union { float f; uint32_t u; } v; v.f = x;
  uint32_t r = v.u + 0x7FFFu + ((v.u >> 16) & 1u);
  return (u16)(r >> 16);
}
__device__ __forceinline__ u32 pack2(float a, float b) { // RNE pair
  return (u32)f2bf(a) | ((u32)f2bf(b) << 16);
}
__device__ __forceinline__ u32 pack2rn(float a, float b) { // fast RN via v_perm (3 VALU)
  union { float f; u32 u; } x, y; x.f = a; y.f = b;
  return __builtin_amdgcn_perm(y.u + 0x8000u, x.u + 0x8000u, 0x07060302u);
}
__device__ __forceinline__ float bf2f(u16 s) {
  union { float f; uint32_t u; } v; v.u = ((uint32_t)s) << 16; return v.f;
}

// async global->LDS, 16B/lane; lds base wave-uniform, hw adds lane*16
__device__ __forceinline__ void gload16(const void* g, void* l) {
  __builtin_amdgcn_global_load_lds((const __attribute__((address_space(1))) void*)g,
                                   (__attribute__((address_space(3))) void*)l,
                                   16, 0, 0);
}

// ---------------- fused prep: casts + weight transposes in ONE dispatch -----------------
// blocks [0,2048): cast x; [2048,10240): cast ctx; [10240,11264): Wq^T;
// [11264,13312): Wkv^T; [13312,14336): Wout^T.
__global__ __launch_bounds__(256) void prep(const float* __restrict__ x,
                                            const float* __restrict__ ctx,
                                            const float* __restrict__ Wq,
                                            const float* __restrict__ Wkv,
                                            const float* __restrict__ Wout,
                                            u16* __restrict__ xb,
                                            u16* __restrict__ ctxb,
                                            u16* __restrict__ WqT,
                                            u16* __restrict__ WkvT,
                                            u16* __restrict__ WoutT) {
  int bid = blockIdx.x;
  if (bid < 10240) {                       // elementwise cast, 4 elems/thread
    const float* src; u16* dst; int blk;
    if (bid < 2048) { src = x; dst = xb; blk = bid; }
    else            { src = ctx; dst = ctxb; blk = bid - 2048; }
    int i = (blk * 256 + threadIdx.x) * 4;
    float4 v = *(const float4*)(src + i);
    uint2 o; o.x = pack2(v.x, v.y); o.y = pack2(v.z, v.w);
    *(uint2*)(dst + i) = o;
    return;
  }
  // transpose+cast W[K][N] -> Wt[N][K]
  __shared__ float tile[32][33];
  const float* W; u16* Wt; int K, N, local, nsh;
  if (bid < 11264)      { W = Wq;   Wt = WqT;   K = 1024; N = 1024; local = bid - 10240; nsh = 5; }
  else if (bid < 13312) { W = Wkv;  Wt = WkvT;  K = 1024; N = 2048; local = bid - 11264; nsh = 6; }
  else                  { W = Wout; Wt = WoutT; K = 1024; N = 1024; local = bid - 13312; nsh = 5; }
  int n0 = (local & ((1 << nsh) - 1)) * 32;
  int k0 = (local >> nsh) * 32;
  int tx = threadIdx.x & 31, ty = threadIdx.x >> 5;   // 32 x 8
  for (int i = ty; i < 32; i += 8)
    tile[i][tx] = W[(size_t)(k0 + i) * N + n0 + tx];
  __syncthreads();
  for (int i = ty; i < 32; i += 8)
    Wt[(size_t)(n0 + i) * K + k0 + tx] = f2bf(tile[tx][i]);
}

// ---------------- kv projection: 256x256 / BK=64 / 8-wave 8-phase pipelined GEMM --------
// Grid = exactly 256 tiles (M=8192 x N=2048) = 1 block/CU, 512 thr, 128 KiB LDS dbuf.
// Schedule (T2+T3+T4+T5): per K-tile 4 phases, each {ds_read subtile || stage 1 half-tile
// (2x global_load_lds) ; raw barrier ; lgkmcnt(0) ; setprio(1) 16 MFMA setprio(0) ;
// counted vmcnt (never 0 in main loop) ; raw barrier}.
// vmcnt ledger (2 loads per half, queue oldest-first), steady state per tile T:
//   enter ph1: [Bb(T), Ab(T)]               (Aa,Ba confirmed by prev ph4 vmcnt(4))
//   ph1 +Aa' -> vmcnt(4) completes Bb(T)  (needed ph2)
//   ph2 +Ba' -> vmcnt(4) completes Ab(T)  (needed ph3)
//   ph3 +Bb' -> no wait
//   ph4 +Ab' -> vmcnt(4) completes Aa',Ba' (needed ph1 of T+1)  -> invariant restored
// Tail tile uses vmcnt(2)/vmcnt(0) at ph1/ph2 (nothing staged).
// LDS rows are region-reordered so stage-half == what the phase consumes:
//   A slot = ih*128 + wr*64 + (i&3)*16 + l15  (row = wr*128 + ih*64 + low6)
//   B slot = jh*128 + wc*32 + (j&1)*16 + l15  (row = wc*64  + jh*32 + low5)
// Swizzle: 16B-chunk index ^= (slot&7), applied to BOTH stage source and read
// (involution; global_load_lds dest stays linear -> rule 21 compliant).
__global__ __launch_bounds__(512, 2) void kv_gemm(const u16* __restrict__ ctxb,
                                                  const u16* __restrict__ WkvT,
                                                  u16* __restrict__ kb,
                                                  u16* __restrict__ vTb) {
  __shared__ __align__(16) u16 As[2][256 * 64];   // 64 KiB
  __shared__ __align__(16) u16 Bs[2][256 * 64];   // 64 KiB
  const int tid = threadIdx.x;
  const int lane = tid & 63;
  const int w = tid >> 6;                 // 0..7
  const int wr = w >> 2, wc = w & 3;      // 2 x 4 waves -> wave panel 128M x 64N
  const int l15 = lane & 15, quad = lane >> 4;
  const int K = 1024;

  // XCD-chunked bijective swizzle: each XCD gets 4 contiguous M-strips x all 8 N-tiles
  int bid = blockIdx.x;
  int wgid = (bid & 7) * 32 + (bid >> 3);
  const int tm = wgid >> 3, tn = wgid & 7;
  const int m0 = tm * 256, n0 = tn * 256;
  const u16* Ag = ctxb + (size_t)m0 * K;
  const u16* Bg = WkvT + (size_t)n0 * K;

  // per-thread stage source offsets (u16 units): row-reorder + chunk XOR pre-swizzle
  size_t offA[2][2], offB[2][2];          // [half][pass] - all uses const-indexed
#pragma unroll
  for (int ah = 0; ah < 2; ++ah)
#pragma unroll
    for (int p = 0; p < 2; ++p) {
      int c = p * 512 + (w << 6) + lane;  // chunk id within 16 KiB region
      int s = ah * 128 + (c >> 3);        // LDS slot (reordered row)
      int col = ((c & 7) ^ (s & 7)) << 3; // pre-swizzled source column (bf16)
      int rA = ((s >> 6) & 1) * 128 + ((s >> 7) & 1) * 64 + (s & 63);
      int rB = ((s >> 5) & 3) * 64 + ((s >> 7) & 1) * 32 + (s & 31);
      offA[ah][p] = (size_t)rA * 1024 + col;
      offB[ah][p] = (size_t)rB * 1024 + col;
    }

#define STAGE_A(bufi, ah, kk) do { \
    gload16(Ag + offA[ah][0] + (kk), &As[bufi][(ah) * 8192 + (w << 9)]); \
    gload16(Ag + offA[ah][1] + (kk), &As[bufi][(ah) * 8192 + 4096 + (w << 9)]); \
  } while (0)
#define STAGE_B(bufi, bh, kk) do { \
    gload16(Bg + offB[bh][0] + (kk), &Bs[bufi][(bh) * 8192 + (w << 9)]); \
    gload16(Bg + offB[bh][1] + (kk), &Bs[bufi][(bh) * 8192 + 4096 + (w << 9)]); \
  } while (0)
#define LDA2(dst, i8, bufi) do { \
    const int _s = ((i8) >> 2) * 128 + wr * 64 + ((i8) & 3) * 16 + l15; \
    const u16* _p = &As[bufi][_s * 64]; const int _x = _s & 7; \
    dst[0] = *(const bf16x8*)&_p[(quad ^ _x) << 3]; \
    dst[1] = *(const bf16x8*)&_p[((quad + 4) ^ _x) << 3]; \
  } while (0)
#define LDB2(dst, j, bufi) do { \
    const int _s = ((j) >> 1) * 128 + wc * 32 + ((j) & 1) * 16 + l15; \
    const u16* _p = &Bs[bufi][_s * 64]; const int _x = _s & 7; \
    dst[0] = *(const bf16x8*)&_p[(quad ^ _x) << 3]; \
    dst[1] = *(const bf16x8*)&_p[((quad + 4) ^ _x) << 3]; \
  } while (0)
#define MF(i0, j0, bb) do { \
    _Pragma("unroll") \
    for (int _i = 0; _i < 4; ++_i) { \
      acc[(i0) + _i][(j0)    ] = __builtin_amdgcn_mfma_f32_16x16x32_bf16(a[_i][0], bb[0][0], acc[(i0) + _i][(j0)    ], 0, 0, 0); \
      acc[(i0) + _i][(j0)    ] = __builtin_amdgcn_mfma_f32_16x16x32_bf16(a[_i][1], bb[0][1], acc[(i0) + _i][(j0)    ], 0, 0, 0); \
      acc[(i0) + _i][(j0) + 1] = __builtin_amdgcn_mfma_f32_16x16x32_bf16(a[_i][0], bb[1][0], acc[(i0) + _i][(j0) + 1], 0, 0, 0); \
      acc[(i0) + _i][(j0) + 1] = __builtin_amdgcn_mfma_f32_16x16x32_bf16(a[_i][1], bb[1][1], acc[(i0) + _i][(j0) + 1], 0, 0, 0); \
    } \
  } while (0)

  f32x4 acc[8][4] = {};
  bf16x8 a[4][2], b[2][2], c2[2][2];

  // prologue: full tile 0 into buf 0; queue = [Aa, Ba, Bb, Ab]
  STAGE_A(0, 0, 0);
  STAGE_B(0, 0, 0);
  STAGE_B(0, 1, 0);
  STAGE_A(0, 1, 0);
  asm volatile("s_waitcnt vmcnt(4)" ::: "memory");   // Aa,Ba ready
  __builtin_amdgcn_s_barrier();

#define KTILE(cur, nxt, kk, STG, W1, W2) do { \
    /* ph1: quadrant (ih0, jh0); reads Aa+Ba regions */ \
    LDB2(b[0], 0, cur); LDB2(b[1], 1, cur); \
    LDA2(a[0], 0, cur); LDA2(a[1], 1, cur); LDA2(a[2], 2, cur); LDA2(a[3], 3, cur); \
    if (STG) STAGE_A(nxt, 0, kk); \
    __builtin_amdgcn_s_barrier(); \
    asm volatile("s_waitcnt lgkmcnt(0)" ::: "memory"); \
    __builtin_amdgcn_s_setprio(1); MF(0, 0, b); __builtin_amdgcn_s_setprio(0); \
    asm volatile("s_waitcnt " W1 ::: "memory"); \
    __builtin_amdgcn_s_barrier(); \
    /* ph2: (ih0, jh1); reads Bb region */ \
    LDB2(c2[0], 2, cur); LDB2(c2[1], 3, cur); \
    if (STG) STAGE_B(nxt, 0, kk); \
    __builtin_amdgcn_s_barrier(); \
    asm volatile("s_waitcnt lgkmcnt(0)" ::: "memory"); \
    __builtin_amdgcn_s_setprio(1); MF(0, 2, c2); __builtin_amdgcn_s_setprio(0); \
    asm volatile("s_waitcnt " W2 ::: "memory"); \
    __builtin_amdgcn_s_barrier(); \
    /* ph3: (ih1, jh0); reads Ab region */ \
    LDA2(a[0], 4, cur); LDA2(a[1], 5, cur); LDA2(a[2], 6, cur); LDA2(a[3], 7, cur); \
    if (STG) STAGE_B(nxt, 1, kk); \
    __builtin_amdgcn_s_barrier(); \
    asm volatile("s_waitcnt lgkmcnt(0)" ::: "memory"); \
    __builtin_amdgcn_s_setprio(1); MF(4, 0, b); __builtin_amdgcn_s_setprio(0); \
    __builtin_amdgcn_s_barrier(); \
    /* ph4: (ih1, jh1); no ds_read */ \
    if (STG) STAGE_A(nxt, 1, kk); \
    __builtin_amdgcn_s_barrier(); \
    __builtin_amdgcn_s_setprio(1); MF(4, 2, c2); __builtin_amdgcn_s_setprio(0); \
    if (STG) { asm volatile("s_waitcnt vmcnt(4)" ::: "memory"); } \
    __builtin_amdgcn_s_barrier(); \
  } while (0)

  for (int T = 0; T < 15; ++T) {
    const int cur = T & 1, nxt = cur ^ 1, kk = (T + 1) * 64;
    KTILE(cur, nxt, kk, 1, "vmcnt(4)", "vmcnt(4)");
  }
  KTILE(1, 0, 0, 0, "vmcnt(2)", "vmcnt(0)");   // tail: nothing staged

  // epilogue: tn<4 -> K (row-major), tn>=4 -> V transposed scatter
  if (tn < 4) {
#pragma unroll
    for (int i8 = 0; i8 < 8; ++i8)
#pragma unroll
      for (int j = 0; j < 4; ++j) {
        int col = n0 + wc * 64 + j * 16 + l15;
#pragma unroll
        for (int r = 0; r < 4; ++r) {
          int row = m0 + wr * 128 + i8 * 16 + quad * 4 + r;
          kb[(size_t)row * 1024 + col] = f2bf(acc[i8][j][r]);
        }
      }
  } else {
    const int bb_ = m0 >> 12;
#pragma unroll
    for (int i8 = 0; i8 < 8; ++i8) {
      int kvr = (m0 & 4095) + wr * 128 + i8 * 16 + quad * 4;
#pragma unroll
      for (int j = 0; j < 4; ++j) {
        int c = (n0 - 1024) + wc * 64 + j * 16 + l15;
        int h = c >> 6, dh = c & 63;
        uint2 st;
        st.x = pack2(acc[i8][j][0], acc[i8][j][1]);
        st.y = pack2(acc[i8][j][2], acc[i8][j][3]);
        *(uint2*)&vTb[((size_t)((bb_ * 16 + h) * 64 + dh)) * NKV_ + kvr] = st;
      }
    }
  }
#undef STAGE_A
#undef STAGE_B
#undef LDA2
#undef LDB2
#undef MF
#undef KTILE
}

// ---------------- q projection: 64x128 tiles -> 256 blocks (full GPU), bf16 out ---------
__global__ __launch_bounds__(256) void q_gemm(const u16* __restrict__ A,
                                              const u16* __restrict__ Bt,
                                              u16* __restrict__ outp) {
  __shared__ __align__(16) u16 As[64 * 32];    // 4 KB
  __shared__ __align__(16) u16 Bs[128 * 32];   // 8 KB
  const int tid = threadIdx.x;
  const int lane = tid & 63;
  const int w = tid >> 6;
  const int wr = w >> 1, wc = w & 1;           // wave covers 32M x 64N
  const int l15 = lane & 15, quad = lane >> 4;
  const int unit = blockIdx.x;
  const int m0 = (unit >> 3) * 64, n0 = (unit & 7) * 128;
  const int K = 1024, N = 1024;

  const u16* Ab = A + (size_t)m0 * K;
  const u16* Bb = Bt + (size_t)n0 * K;
  f32x4 acc[2][4] = {};

  const int ar = tid >> 2, ac = (tid & 3) << 3;          // A: 256 chunks, 1/thread
  const int q1 = w * 64 + lane, q2 = q1 + 256;           // B: 512 chunks, 2/thread
  const int br1 = q1 >> 2, bc1 = (q1 & 3) << 3;
  const int br2 = q2 >> 2, bc2 = (q2 & 3) << 3;

  for (int k0 = 0; k0 < K; k0 += 32) {
    __syncthreads();
    gload16(Ab + (size_t)ar * K + k0 + ac, &As[w * 512]);
    gload16(Bb + (size_t)br1 * K + k0 + bc1, &Bs[w * 512]);
    gload16(Bb + (size_t)br2 * K + k0 + bc2, &Bs[2048 + w * 512]);
    __syncthreads();
    bf16x8 af[2], bfr[4];
#pragma unroll
    for (int i = 0; i < 2; ++i)
      af[i] = *(const bf16x8*)&As[(wr * 32 + i * 16 + l15) * 32 + quad * 8];
#pragma unroll
    for (int j = 0; j < 4; ++j)
      bfr[j] = *(const bf16x8*)&Bs[(wc * 64 + j * 16 + l15) * 32 + quad * 8];
#pragma unroll
    for (int i = 0; i < 2; ++i)
#pragma unroll
      for (int j = 0; j < 4; ++j)
        acc[i][j] = __builtin_amdgcn_mfma_f32_16x16x32_bf16(af[i], bfr[j], acc[i][j], 0, 0, 0);
  }

#pragma unroll
  for (int i = 0; i < 2; ++i)
#pragma unroll
    for (int j = 0; j < 4; ++j) {
      int col = n0 + wc * 64 + j * 16 + l15;
#pragma unroll
      for (int r = 0; r < 4; ++r) {
        int row = m0 + wr * 32 + i * 16 + quad * 4 + r;
        outp[(size_t)row * N + col] = f2bf(acc[i][j][r]);
      }
    }
}

// ---------------- out-proj GEMM: 64x128 tiles -> 256 blocks (full GPU) ------------------
__global__ __launch_bounds__(256) void out_gemm(const u16* __restrict__ A,
                                                const u16* __restrict__ Bt,
                                                float* __restrict__ Cout,
                                                const float* __restrict__ bias) {
  __shared__ __align__(16) u16 As[64 * 32];    // 4 KB
  __shared__ __align__(16) u16 Bs[128 * 32];   // 8 KB
  const int tid = threadIdx.x;
  const int lane = tid & 63;
  const int w = tid >> 6;
  const int wr = w >> 1, wc = w & 1;           // wave covers 32M x 64N
  const int l15 = lane & 15, quad = lane >> 4;
  const int unit = blockIdx.x;
  const int m0 = (unit >> 3) * 64, n0 = (unit & 7) * 128;
  const int K = 1024, N = 1024;

  const u16* Ab = A + (size_t)m0 * K;
  const u16* Bb = Bt + (size_t)n0 * K;
  f32x4 acc[2][4] = {};

  const int ar = tid >> 2, ac = (tid & 3) << 3;          // A: 256 chunks, 1/thread
  const int q1 = w * 64 + lane, q2 = q1 + 256;           // B: 512 chunks, 2/thread
  const int br1 = q1 >> 2, bc1 = (q1 & 3) << 3;
  const int br2 = q2 >> 2, bc2 = (q2 & 3) << 3;

  for (int k0 = 0; k0 < K; k0 += 32) {
    __syncthreads();
    gload16(Ab + (size_t)ar * K + k0 + ac, &As[w * 512]);
    gload16(Bb + (size_t)br1 * K + k0 + bc1, &Bs[w * 512]);
    gload16(Bb + (size_t)br2 * K + k0 + bc2, &Bs[2048 + w * 512]);
    __syncthreads();
    bf16x8 af[2], bfr[4];
#pragma unroll
    for (int i = 0; i < 2; ++i)
      af[i] = *(const bf16x8*)&As[(wr * 32 + i * 16 + l15) * 32 + quad * 8];
#pragma unroll
    for (int j = 0; j < 4; ++j)
      bfr[j] = *(const bf16x8*)&Bs[(wc * 64 + j * 16 + l15) * 32 + quad * 8];
#pragma unroll
    for (int i = 0; i < 2; ++i)
#pragma unroll
      for (int j = 0; j < 4; ++j)
        acc[i][j] = __builtin_amdgcn_mfma_f32_16x16x32_bf16(af[i], bfr[j], acc[i][j], 0, 0, 0);
  }

#pragma unroll
  for (int i = 0; i < 2; ++i)
#pragma unroll
    for (int j = 0; j < 4; ++j) {
      int col = n0 + wc * 64 + j * 16 + l15;
      float bv = bias[col];
#pragma unroll
      for (int r = 0; r < 4; ++r) {
        int row = m0 + wr * 32 + i * 16 + quad * 4 + r;
        Cout[(size_t)row * N + col] = acc[i][j][r] + bv;
      }
    }
}

// ---------------- flash attention (round-5 proven): kv-sliced waves ---------------------
// Block = 64 q-rows x one (b,h); 256 thr / 4 waves; 2 blocks/CU (53 KB LDS).
// Grid x=bh so the 16 q-blocks sharing one K/V head get the same blockid%8 -> same XCD L2.
__global__ __launch_bounds__(256, 2) void attn_kernel(const u16* __restrict__ qg,
                                                      const u16* __restrict__ kb,
                                                      const u16* __restrict__ vT,
                                                      u16* __restrict__ attn_out) {
  __shared__ __align__(16) u16 Ks[128 * 64];       // [kv][dh], 16B groups XOR-swizzled
  __shared__ __align__(16) u16 Vs[64 * 128];       // [dh][kv], XOR-swizzled (16 groups/row)
  __shared__ __align__(16) u32 P32[4 * 4 * 16 * 20]; // [w][t][q=l15][20]: wave-private pairs
  __shared__ float Lr[4][4][16];                   // [w][t][q] partial l

  const int tid = threadIdx.x;
  const int lane = tid & 63;
  const int w = tid >> 6;
  const int l15 = lane & 15, quad = lane >> 4;
  const int bh = blockIdx.x, b = bh >> 4, h = bh & 15;
  const int q0 = blockIdx.y * 64;

  const float SC = 0.125f * 1.44269504088896340736f;   // dh^-0.5 * log2(e)
  union { u16 s[8]; bf16x8 v; } qf[4][2];
#pragma unroll
  for (int t = 0; t < 4; ++t)
#pragma unroll
    for (int kc = 0; kc < 2; ++kc) {
      const u16* qp = qg + (size_t)(b * NQ_ + q0 + t * 16 + l15) * INNER_ + h * 64 +
                      kc * 32 + quad * 8;
      union { u16 s[8]; uint4 u; } tmp;
      tmp.u = *(const uint4*)qp;
#pragma unroll
      for (int e = 0; e < 8; ++e) qf[t][kc].s[e] = f2bf(bf2f(tmp.s[e]) * SC);
    }

  f32x4 Oacc[4][4] = {};
  float l_lane[4] = {0.f, 0.f, 0.f, 0.f};

  for (int it = 0; it < 32; ++it) {
    const int j0 = it * 128;
    __syncthreads();
#pragma unroll
    for (int i = 0; i < 4; ++i) {
      int s = i * 256 + tid;
      int kr = s >> 3, kg = (s ^ kr) & 7;
      gload16(kb + (size_t)(b * NKV_ + j0 + kr) * 1024 + h * 64 + kg * 8,
              &Ks[(i * 256 + w * 64) * 8]);
      int vr = s >> 4, vg = (s ^ vr) & 15;
      gload16(vT + (size_t)(bh * 64 + vr) * NKV_ + j0 + vg * 8,
              &Vs[(i * 256 + w * 64) * 8]);
    }
    __syncthreads();

    bf16x8 kf[2][2];
#pragma unroll
    for (int kvt = 0; kvt < 2; ++kvt)
#pragma unroll
      for (int kc = 0; kc < 2; ++kc)
        kf[kvt][kc] = *(const bf16x8*)
          &Ks[(w * 32 + kvt * 16 + l15) * 64 + (((kc * 4 + quad) ^ l15) & 7) * 8];
    f32x4 sacc[2][4] = {};
#pragma unroll
    for (int kvt = 0; kvt < 2; ++kvt)
#pragma unroll
      for (int t = 0; t < 4; ++t)
#pragma unroll
        for (int kc = 0; kc < 2; ++kc)
          sacc[kvt][t] = __builtin_amdgcn_mfma_f32_16x16x32_bf16(
              kf[kvt][kc], qf[t][kc].v, sacc[kvt][t], 0, 0, 0);

#pragma unroll
    for (int kvt = 0; kvt < 2; ++kvt)
#pragma unroll
      for (int t = 0; t < 4; ++t) {
        float p0 = __builtin_amdgcn_exp2f(sacc[kvt][t][0]);
        float p1 = __builtin_amdgcn_exp2f(sacc[kvt][t][1]);
        float p2 = __builtin_amdgcn_exp2f(sacc[kvt][t][2]);
        float p3 = __builtin_amdgcn_exp2f(sacc[kvt][t][3]);
        l_lane[t] += (p0 + p1) + (p2 + p3);
        uint2 pk; pk.x = pack2rn(p0, p1); pk.y = pack2rn(p2, p3);
        *(uint2*)&P32[((w * 4 + t) * 16 + l15) * 20 + kvt * 8 + quad * 2] = pk;
      }

    bf16x8 vf[4], pf[4];
#pragma unroll
    for (int d = 0; d < 4; ++d)
      vf[d] = *(const bf16x8*)
        &Vs[(d * 16 + l15) * 128 + (((w * 4 + quad) ^ l15) & 15) * 8];
#pragma unroll
    for (int t = 0; t < 4; ++t)
      pf[t] = *(const bf16x8*)&P32[((w * 4 + t) * 16 + l15) * 20 + quad * 4];
#pragma unroll
    for (int d = 0; d < 4; ++d)
#pragma unroll
      for (int t = 0; t < 4; ++t)
        Oacc[d][t] = __builtin_amdgcn_mfma_f32_16x16x32_bf16(vf[d], pf[t], Oacc[d][t],
                                                             0, 0, 0);
  }

#pragma unroll
  for (int t = 0; t < 4; ++t) {
    l_lane[t] += __shfl_xor(l_lane[t], 16);
    l_lane[t] += __shfl_xor(l_lane[t], 32);
  }
  if (quad == 0) {
#pragma unroll
    for (int t = 0; t < 4; ++t) Lr[w][t][l15] = l_lane[t];
  }
  __syncthreads();
  float inv = 1.0f / (Lr[0][w][l15] + Lr[1][w][l15] + Lr[2][w][l15] + Lr[3][w][l15]);

  float* red = (float*)P32;
  u16* ob = attn_out + (size_t)(b * NQ_ + q0 + w * 16 + l15) * INNER_ + h * 64;
#pragma unroll
  for (int d = 0; d < 4; ++d) {
    __syncthreads();
#pragma unroll
    for (int t = 0; t < 4; ++t)
      *(f32x4*)&red[(w * 4 + t) * 256 + quad * 64 + l15 * 4] = Oacc[d][t];
    __syncthreads();
    f32x4 r = *(const f32x4*)&red[(0 * 4 + w) * 256 + quad * 64 + l15 * 4];
#pragma unroll
    for (int ww = 1; ww < 4; ++ww) {
      f32x4 c = *(const f32x4*)&red[(ww * 4 + w) * 256 + quad * 64 + l15 * 4];
      r[0] += c[0]; r[1] += c[1]; r[2] += c[2]; r[3] += c[3];
    }
    *(u32*)(ob + d * 16 + quad * 4)     = pack2(r[0] * inv, r[1] * inv);
    *(u32*)(ob + d * 16 + quad * 4 + 2) = pack2(r[2] * inv, r[3] * inv);
  }
}

// ---------------- driver ----------------
extern "C" void kernel_launch(void* const* d_in, const int* in_sizes, int n_in,
                              void* d_out, int out_size, void* d_ws, size_t ws_size,
                              hipStream_t stream) {
  const float* x    = (const float*)d_in[0];
  const float* ctx  = (const float*)d_in[1];
  const float* Wq   = (const float*)d_in[2];
  const float* Wkv  = (const float*)d_in[3];
  const float* Wout = (const float*)d_in[4];
  const float* bout = (const float*)d_in[5];

  char* ws = (char*)d_ws;
  u16* xb    = (u16*)(ws + (size_t)( 0u << 20));  // 4 MB  [dead after q_gemm]
  u16* ab    = (u16*)(ws + (size_t)( 0u << 20));  // 4 MB  [reuses xb]
  u16* ctxb  = (u16*)(ws + (size_t)( 4u << 20));  // 16 MB [dead after kv_gemm]
  u16* WqT   = (u16*)(ws + (size_t)(20u << 20));  // 2 MB
  u16* WkvT  = (u16*)(ws + (size_t)(22u << 20));  // 4 MB
  u16* WoutT = (u16*)(ws + (size_t)(26u << 20));  // 2 MB
  u16* qb    = (u16*)(ws + (size_t)(28u << 20));  // 4 MB
  u16* kb    = (u16*)(ws + (size_t)(32u << 20));  // 16 MB
  u16* vTb   = (u16*)(ws + (size_t)(48u << 20));  // 16 MB

  // casts + weight transposes in one dispatch
  prep<<<14336, 256, 0, stream>>>(x, ctx, Wq, Wkv, Wout, xb, ctxb, WqT, WkvT, WoutT);
  // q projection: 256 blocks, 64x128 tiles (full GPU)
  q_gemm<<<256, 256, 0, stream>>>(xb, WqT, qb);
  // kv projection: 256 blocks of 256x256, 8-phase pipelined, 1 block/CU
  kv_gemm<<<256, 512, 0, stream>>>(ctxb, WkvT, kb, vTb);
  // fused softmax attention: 512 blocks x 256 threads, x=bh for XCD L2 locality
  attn_kernel<<<dim3(32, 16), 256, 0, stream>>>(qb, kb, vTb, ab);
  // out = attn Wout + b_out : fp32, 256 blocks
  out_gemm<<<256, 256, 0, stream>>>(ab, WoutT, (float*)d_out, bout);
}